// Round 1
// baseline (167.207 us; speedup 1.0000x reference)
//
#include <hip/hip_runtime.h>

typedef float f32x4 __attribute__((ext_vector_type(4)));
typedef short bf16x8 __attribute__((ext_vector_type(8)));

__device__ __forceinline__ unsigned short f2bf(float f) {
  unsigned int u = __builtin_bit_cast(unsigned int, f);
  u += 0x7fffu + ((u >> 16) & 1u);
  return (unsigned short)(u >> 16);
}
__device__ __forceinline__ float bf2f(unsigned short s) {
  unsigned int u = ((unsigned int)s) << 16;
  return __builtin_bit_cast(float, u);
}

// ---------------- weight packing: f32 -> bf16, pre-transposed [N][K] ----------------
__global__ __launch_bounds__(256) void pack_w(
    const float* __restrict__ WQ, const float* __restrict__ WK,
    const float* __restrict__ WV, const float* __restrict__ WG,
    const float* __restrict__ WO, const float* __restrict__ F1,
    const float* __restrict__ F2,
    unsigned short* __restrict__ qg, unsigned short* __restrict__ kv,
    unsigned short* __restrict__ wo, unsigned short* __restrict__ f1,
    unsigned short* __restrict__ f2)
{
  int i = blockIdx.x * 256 + threadIdx.x;
  if (i < 131072) {                      // [WqT | WgT]  512x256
    int n = i >> 8, d = i & 255;
    float v = (n < 256) ? WQ[((n >> 6) * 256 + d) * 64 + (n & 63)]
                        : WG[d * 256 + (n - 256)];
    qg[i] = f2bf(v);
  } else if (i < 262144) {               // [WkT | WvT]  512x256
    int j = i - 131072; int n = j >> 8, d = j & 255;
    float v = (n < 256) ? WK[((n >> 6) * 256 + d) * 64 + (n & 63)]
                        : WV[(((n - 256) >> 6) * 256 + d) * 64 + ((n - 256) & 63)];
    kv[j] = f2bf(v);
  } else if (i < 327680) {               // WoT 256x256
    int j = i - 262144; int n = j >> 8, d = j & 255;
    wo[j] = f2bf(WO[d * 256 + n]);
  } else if (i < 458752) {               // F1T 512x256
    int j = i - 327680; int n = j >> 8, d = j & 255;
    f1[j] = f2bf(F1[d * 512 + n]);
  } else if (i < 589824) {               // F2T 256x512
    int j = i - 458752; int n = j >> 9, k = j & 511;
    f2[j] = f2bf(F2[k * 256 + n]);
  }
}

// ---------------- LayerNorm over 256, one wave per row, output bf16 ----------------
__global__ __launch_bounds__(256) void ln_fwd(
    const float* __restrict__ X, const float* __restrict__ W,
    const float* __restrict__ Bv, unsigned short* __restrict__ Y)
{
  int lane = threadIdx.x & 63;
  size_t row = (size_t)blockIdx.x * 4 + (threadIdx.x >> 6);
  const float4 v = *reinterpret_cast<const float4*>(X + row * 256 + lane * 4);
  float s = v.x + v.y + v.z + v.w;
  #pragma unroll
  for (int off = 1; off < 64; off <<= 1) s += __shfl_xor(s, off);
  float mean = s * (1.0f / 256.0f);
  float dx = v.x - mean, dy = v.y - mean, dz = v.z - mean, dw = v.w - mean;
  float q = dx * dx + dy * dy + dz * dz + dw * dw;
  #pragma unroll
  for (int off = 1; off < 64; off <<= 1) q += __shfl_xor(q, off);
  float rstd = rsqrtf(q * (1.0f / 256.0f) + 1e-5f);
  float4 wv = *reinterpret_cast<const float4*>(W + lane * 4);
  float4 bv = *reinterpret_cast<const float4*>(Bv + lane * 4);
  ushort4 o;
  o.x = f2bf(dx * rstd * wv.x + bv.x);
  o.y = f2bf(dy * rstd * wv.y + bv.y);
  o.z = f2bf(dz * rstd * wv.z + bv.z);
  o.w = f2bf(dw * rstd * wv.w + bv.w);
  *reinterpret_cast<ushort4*>(Y + row * 256 + lane * 4) = o;
}

// ---------------- NT GEMM: A[M,K]bf16 @ B[N,K]bf16 -> epilogue ----------------
// tile 128x64, BK=64, 4 waves (2x2), each wave 64x32 = 4x2 fragments of 16x16x32.
// EPI: 0=QG(split bf16), 1=KV(bf16 + V transposed), 2=+resid->f32,
//      3=+bias,leakyrelu->bf16(stride 512), 4=+bias+resid->f32
template<int EPI>
__global__ __launch_bounds__(256) void gemm_nt(
    const unsigned short* __restrict__ A, const unsigned short* __restrict__ Bw,
    int K, unsigned short* __restrict__ o0, unsigned short* __restrict__ o1,
    const float* __restrict__ bias, const float* __restrict__ resid,
    float* __restrict__ of)
{
  __shared__ __align__(16) char sA[128 * 128];
  __shared__ __align__(16) char sB[64 * 128];
  const int tid = threadIdx.x, lane = tid & 63, w = tid >> 6;
  const int m0 = blockIdx.y * 128, n0 = blockIdx.x * 64;
  const int wr = (w >> 1) * 64, wc = (w & 1) * 32;
  const char* Ab = (const char*)A + (size_t)m0 * K * 2;
  const char* Bb = (const char*)Bw + (size_t)n0 * K * 2;
  f32x4 acc[4][2] = {};

  for (int kt = 0; kt < K * 2; kt += 128) {   // kt = k-offset in bytes
    #pragma unroll
    for (int i = 0; i < 4; ++i) {
      int p = (tid + i * 256) * 16, row = p >> 7, inner = p & 127;
      uint4 v = *reinterpret_cast<const uint4*>(Ab + (size_t)row * (K * 2) + kt + inner);
      *reinterpret_cast<uint4*>(sA + row * 128 + (inner ^ ((row & 7) << 4))) = v;
    }
    #pragma unroll
    for (int i = 0; i < 2; ++i) {
      int p = (tid + i * 256) * 16, row = p >> 7, inner = p & 127;
      uint4 v = *reinterpret_cast<const uint4*>(Bb + (size_t)row * (K * 2) + kt + inner);
      *reinterpret_cast<uint4*>(sB + row * 128 + (inner ^ ((row & 7) << 4))) = v;
    }
    __syncthreads();
    #pragma unroll
    for (int kk = 0; kk < 2; ++kk) {
      const int ib = kk * 64 + ((lane >> 4) * 16);
      bf16x8 af[4], bfr[2];
      #pragma unroll
      for (int rf = 0; rf < 4; ++rf) {
        int row = wr + rf * 16 + (lane & 15);
        af[rf] = *reinterpret_cast<const bf16x8*>(sA + row * 128 + (ib ^ ((row & 7) << 4)));
      }
      #pragma unroll
      for (int cf = 0; cf < 2; ++cf) {
        int row = wc + cf * 16 + (lane & 15);
        bfr[cf] = *reinterpret_cast<const bf16x8*>(sB + row * 128 + (ib ^ ((row & 7) << 4)));
      }
      #pragma unroll
      for (int rf = 0; rf < 4; ++rf)
        #pragma unroll
        for (int cf = 0; cf < 2; ++cf)
          acc[rf][cf] = __builtin_amdgcn_mfma_f32_16x16x32_bf16(af[rf], bfr[cf], acc[rf][cf], 0, 0, 0);
    }
    __syncthreads();
  }

  #pragma unroll
  for (int rf = 0; rf < 4; ++rf) {
    #pragma unroll
    for (int cf = 0; cf < 2; ++cf) {
      const int r0 = m0 + wr + rf * 16 + ((lane >> 4) * 4);
      const int col = n0 + wc + cf * 16 + (lane & 15);
      f32x4 v = acc[rf][cf];
      if constexpr (EPI == 0) {
        unsigned short* dst = (n0 < 256) ? o0 : o1;
        int c = col & 255;
        #pragma unroll
        for (int j = 0; j < 4; ++j) dst[(size_t)(r0 + j) * 256 + c] = f2bf(v[j]);
      } else if constexpr (EPI == 1) {
        if (n0 < 256) {
          #pragma unroll
          for (int j = 0; j < 4; ++j) o0[(size_t)(r0 + j) * 256 + col] = f2bf(v[j]);
        } else {
          int vc = col - 256, hh = vc >> 6, e = vc & 63;
          int bh = (r0 >> 10) * 4 + hh, s0 = r0 & 1023;
          ushort4 pk;
          pk.x = f2bf(v[0]); pk.y = f2bf(v[1]); pk.z = f2bf(v[2]); pk.w = f2bf(v[3]);
          *reinterpret_cast<ushort4*>(o1 + (((size_t)bh * 64 + e) << 10) + s0) = pk;
        }
      } else if constexpr (EPI == 2) {
        #pragma unroll
        for (int j = 0; j < 4; ++j) {
          size_t idx = (size_t)(r0 + j) * 256 + col;
          of[idx] = v[j] + resid[idx];
        }
      } else if constexpr (EPI == 3) {
        float bc = bias[col];
        #pragma unroll
        for (int j = 0; j < 4; ++j) {
          float t = v[j] + bc;
          o0[(size_t)(r0 + j) * 512 + col] = f2bf(t >= 0.0f ? t : 0.01f * t);
        }
      } else {
        float bc = bias[col];
        #pragma unroll
        for (int j = 0; j < 4; ++j) {
          size_t idx = (size_t)(r0 + j) * 256 + col;
          of[idx] = v[j] + bc + resid[idx];
        }
      }
    }
  }
}

// ---------------- retention: per (b,h,q-tile64) causal decay attention ----------------
// Q[tok,256] K[tok,256] bf16 head-sliced; Vt[B,H,64,S] bf16; out AY = swish(G)*(GN(Yh)*gnw+gnb)
__global__ __launch_bounds__(256) void attn_ret(
    const unsigned short* __restrict__ Qb, const unsigned short* __restrict__ Kb,
    const unsigned short* __restrict__ Vt, const unsigned short* __restrict__ Gb,
    const float* __restrict__ gnw, const float* __restrict__ gnb,
    unsigned short* __restrict__ AY)
{
  __shared__ __align__(16) char sQ[64 * 128];
  __shared__ __align__(16) char sK[64 * 128];
  __shared__ __align__(16) char sV[64 * 128];
  __shared__ __align__(16) char sP[64 * 128];
  const int tid = threadIdx.x, lane = tid & 63, w = tid >> 6;
  const int qt = blockIdx.x, bh = blockIdx.y, b = bh >> 2, h = bh & 3;

  const float la = logf(1.0f / 32.0f), lb = logf(1.0f / 512.0f);
  const float gamma = 1.0f - expf(la + (lb - la) * ((float)h * (1.0f / 3.0f)));
  const float lg = log2f(gamma);

  // stage Q tile (once)
  {
    const char* Qg = (const char*)Qb + (((size_t)(b * 1024 + qt * 64)) * 256 + h * 64) * 2;
    #pragma unroll
    for (int i = 0; i < 2; ++i) {
      int p = (tid + i * 256) * 16, row = p >> 7, inner = p & 127;
      uint4 v = *reinterpret_cast<const uint4*>(Qg + (size_t)row * 512 + inner);
      *reinterpret_cast<uint4*>(sQ + row * 128 + (inner ^ ((row & 7) << 4))) = v;
    }
  }

  const int nloc_b = w * 16 + ((lane >> 4) * 4);
  float Aj[4], Bcf[4];
  #pragma unroll
  for (int j = 0; j < 4; ++j) Aj[j] = exp2f((float)(qt * 64 + nloc_b + j) * lg);
  #pragma unroll
  for (int cf = 0; cf < 4; ++cf) Bcf[cf] = exp2f(-(float)(cf * 16 + (lane & 15)) * lg);
  const float g64 = exp2f(-64.0f * lg);

  f32x4 o[4] = {};
  for (int t = 0; t <= qt; ++t) {
    const int m0 = t * 64;
    {
      const char* Kg = (const char*)Kb + (((size_t)(b * 1024 + m0)) * 256 + h * 64) * 2;
      const char* Vg = (const char*)Vt + (((size_t)bh * 64) * 1024 + m0) * 2;
      #pragma unroll
      for (int i = 0; i < 2; ++i) {
        int p = (tid + i * 256) * 16, row = p >> 7, inner = p & 127;
        uint4 kv4 = *reinterpret_cast<const uint4*>(Kg + (size_t)row * 512 + inner);
        *reinterpret_cast<uint4*>(sK + row * 128 + (inner ^ ((row & 7) << 4))) = kv4;
        uint4 vv4 = *reinterpret_cast<const uint4*>(Vg + (size_t)row * 2048 + inner);
        *reinterpret_cast<uint4*>(sV + row * 128 + (inner ^ ((row & 7) << 4))) = vv4;
      }
    }
    __syncthreads();

    // QK^T: s[cf] = Q(16 rows of this wave) x K(64 keys)
    f32x4 s[4] = {};
    #pragma unroll
    for (int kk = 0; kk < 2; ++kk) {
      const int ib = kk * 64 + ((lane >> 4) * 16);
      int qrow = w * 16 + (lane & 15);
      bf16x8 aq = *reinterpret_cast<const bf16x8*>(sQ + qrow * 128 + (ib ^ ((qrow & 7) << 4)));
      #pragma unroll
      for (int cf = 0; cf < 4; ++cf) {
        int kr = cf * 16 + (lane & 15);
        bf16x8 bk = *reinterpret_cast<const bf16x8*>(sK + kr * 128 + (ib ^ ((kr & 7) << 4)));
        s[cf] = __builtin_amdgcn_mfma_f32_16x16x32_bf16(aq, bk, s[cf], 0, 0, 0);
      }
    }

    // decay + mask, write P (wave-private rows) as bf16
    const bool diag = (t == qt);
    #pragma unroll
    for (int cf = 0; cf < 4; ++cf) {
      const int mloc = cf * 16 + (lane & 15);
      #pragma unroll
      for (int j = 0; j < 4; ++j) {
        float p = s[cf][j] * (Aj[j] * Bcf[cf]);
        if (diag && (nloc_b + j - mloc) < 0) p = 0.0f;
        int pr = nloc_b + j;
        *reinterpret_cast<unsigned short*>(sP + pr * 128 + ((mloc * 2) ^ ((pr & 7) << 4))) = f2bf(p);
      }
    }

    // PV: o[cf(e-block)] += P x Vt
    #pragma unroll
    for (int kk = 0; kk < 2; ++kk) {
      const int ib = kk * 64 + ((lane >> 4) * 16);
      int pr = w * 16 + (lane & 15);
      bf16x8 ap = *reinterpret_cast<const bf16x8*>(sP + pr * 128 + (ib ^ ((pr & 7) << 4)));
      #pragma unroll
      for (int cf = 0; cf < 4; ++cf) {
        int vr = cf * 16 + (lane & 15);
        bf16x8 bv = *reinterpret_cast<const bf16x8*>(sV + vr * 128 + (ib ^ ((vr & 7) << 4)));
        o[cf] = __builtin_amdgcn_mfma_f32_16x16x32_bf16(ap, bv, o[cf], 0, 0, 0);
      }
    }
    #pragma unroll
    for (int j = 0; j < 4; ++j) Aj[j] *= g64;
    __syncthreads();
  }

  // GroupNorm per (token,head) over 64 + gn affine + swish(G) gate -> bf16
  float gw[4], gb[4];
  #pragma unroll
  for (int cf = 0; cf < 4; ++cf) {
    int col = h * 64 + cf * 16 + (lane & 15);
    gw[cf] = gnw[col]; gb[cf] = gnb[col];
  }
  const int tokb = b * 1024 + qt * 64 + nloc_b;
  #pragma unroll
  for (int j = 0; j < 4; ++j) {
    float sm = 0.0f, sq = 0.0f;
    #pragma unroll
    for (int cf = 0; cf < 4; ++cf) { float xv = o[cf][j]; sm += xv; sq += xv * xv; }
    #pragma unroll
    for (int off = 1; off < 16; off <<= 1) { sm += __shfl_xor(sm, off); sq += __shfl_xor(sq, off); }
    float mean = sm * (1.0f / 64.0f);
    float var = sq * (1.0f / 64.0f) - mean * mean;
    float rstd = rsqrtf(var + 1e-5f);
    size_t tok = (size_t)(tokb + j);
    #pragma unroll
    for (int cf = 0; cf < 4; ++cf) {
      int col = h * 64 + cf * 16 + (lane & 15);
      float yn = (o[cf][j] - mean) * rstd * gw[cf] + gb[cf];
      float g = bf2f(Gb[tok * 256 + col]);
      float sg = g / (1.0f + expf(-g));
      AY[tok * 256 + col] = f2bf(yn * sg);
    }
  }
}

// ---------------- launch ----------------
extern "C" void kernel_launch(void* const* d_in, const int* in_sizes, int n_in,
                              void* d_out, int out_size, void* d_ws, size_t ws_size,
                              hipStream_t stream) {
  const float* x     = (const float*)d_in[0];
  const float* y     = (const float*)d_in[1];
  const float* ln1_w = (const float*)d_in[2];
  const float* ln1_b = (const float*)d_in[3];
  const float* W_Q   = (const float*)d_in[4];
  const float* W_K   = (const float*)d_in[5];
  const float* W_V   = (const float*)d_in[6];
  const float* gn_w  = (const float*)d_in[7];
  const float* gn_b  = (const float*)d_in[8];
  const float* W_G   = (const float*)d_in[9];
  const float* W_O   = (const float*)d_in[10];
  const float* ln2_w = (const float*)d_in[11];
  const float* ln2_b = (const float*)d_in[12];
  const float* ff_w1 = (const float*)d_in[13];
  const float* ff_b1 = (const float*)d_in[14];
  const float* ff_w2 = (const float*)d_in[15];
  const float* ff_b2 = (const float*)d_in[16];

  char* ws = (char*)d_ws;
  const size_t MB = 1048576;
  unsigned short* XN  = (unsigned short*)(ws + 0 * MB);     // 8MB, later reused under H
  unsigned short* ZN  = (unsigned short*)(ws + 8 * MB);     // 8MB, later AY
  unsigned short* QB  = (unsigned short*)(ws + 16 * MB);    // 8MB, later x1 low
  unsigned short* KB  = (unsigned short*)(ws + 24 * MB);    // 8MB, later x1 high
  unsigned short* VT  = (unsigned short*)(ws + 32 * MB);    // 8MB, later x1n
  unsigned short* GB  = (unsigned short*)(ws + 40 * MB);    // 8MB
  unsigned short* WQG = (unsigned short*)(ws + 48 * MB);            // 256KB
  unsigned short* WKV = (unsigned short*)(ws + 48 * MB + 262144);   // 256KB
  unsigned short* WOp = (unsigned short*)(ws + 48 * MB + 524288);   // 128KB
  unsigned short* F1p = (unsigned short*)(ws + 48 * MB + 655360);   // 256KB
  unsigned short* F2p = (unsigned short*)(ws + 48 * MB + 917504);   // 256KB
  float*          X1  = (float*)(ws + 16 * MB);             // 16MB f32
  unsigned short* X1N = (unsigned short*)(ws + 32 * MB);    // 8MB
  unsigned short* H   = (unsigned short*)(ws + 0 * MB);     // 16MB
  unsigned short* AY  = ZN;
  float* out = (float*)d_out;

  pack_w<<<2304, 256, 0, stream>>>(W_Q, W_K, W_V, W_G, W_O, ff_w1, ff_w2,
                                   WQG, WKV, WOp, F1p, F2p);
  ln_fwd<<<4096, 256, 0, stream>>>(x, ln1_w, ln1_b, XN);
  ln_fwd<<<4096, 256, 0, stream>>>(y, ln1_w, ln1_b, ZN);
  // Q | G  = xn @ [WqT|WgT]
  gemm_nt<0><<<dim3(8, 128), 256, 0, stream>>>(XN, WQG, 256, QB, GB, nullptr, nullptr, nullptr);
  // K | Vt = zn @ [WkT|WvT]
  gemm_nt<1><<<dim3(8, 128), 256, 0, stream>>>(ZN, WKV, 256, KB, VT, nullptr, nullptr, nullptr);
  // retention + GN + gate -> AY (reuses ZN)
  attn_ret<<<dim3(16, 64), 256, 0, stream>>>(QB, KB, VT, GB, gn_w, gn_b, AY);
  // x1 = AY @ WoT + x
  gemm_nt<2><<<dim3(4, 128), 256, 0, stream>>>(AY, WOp, 256, nullptr, nullptr, nullptr, x, X1);
  // x1n = LN(x1)
  ln_fwd<<<4096, 256, 0, stream>>>(X1, ln2_w, ln2_b, X1N);
  // H = leakyrelu(x1n @ F1T + b1)
  gemm_nt<3><<<dim3(8, 128), 256, 0, stream>>>(X1N, F1p, 256, H, nullptr, ff_b1, nullptr, nullptr);
  // out = H @ F2T + b2 + x1
  gemm_nt<4><<<dim3(4, 128), 256, 0, stream>>>(H, F2p, 512, nullptr, nullptr, ff_b2, X1, out);
}

// Round 2
// 109.528 us; speedup vs baseline: 1.5266x; 1.5266x over previous
//
#include <hip/hip_runtime.h>

typedef float f32x4 __attribute__((ext_vector_type(4)));
typedef short bf16x8 __attribute__((ext_vector_type(8)));

__device__ __forceinline__ unsigned short f2bf(float f) {
  unsigned int u = __builtin_bit_cast(unsigned int, f);
  u += 0x7fffu + ((u >> 16) & 1u);
  return (unsigned short)(u >> 16);
}
__device__ __forceinline__ float bf2f(unsigned short s) {
  unsigned int u = ((unsigned int)s) << 16;
  return __builtin_bit_cast(float, u);
}

// async global->LDS, 16B per lane. LDS dest = wave-uniform base + lane*16.
__device__ __forceinline__ void gll16(const void* src, void* dst) {
  __builtin_amdgcn_global_load_lds((const __attribute__((address_space(1))) void*)src,
                                   (__attribute__((address_space(3))) void*)dst, 16, 0, 0);
}

// ---------------- weight packing: f32 -> bf16, pre-transposed [N][K] ----------------
__global__ __launch_bounds__(256) void pack_w(
    const float* __restrict__ WQ, const float* __restrict__ WK,
    const float* __restrict__ WV, const float* __restrict__ WG,
    const float* __restrict__ WO, const float* __restrict__ F1,
    const float* __restrict__ F2,
    unsigned short* __restrict__ qg, unsigned short* __restrict__ kv,
    unsigned short* __restrict__ wo, unsigned short* __restrict__ f1,
    unsigned short* __restrict__ f2)
{
  int i = blockIdx.x * 256 + threadIdx.x;
  if (i < 131072) {                      // [WqT | WgT]  512x256
    int n = i >> 8, d = i & 255;
    float v = (n < 256) ? WQ[((n >> 6) * 256 + d) * 64 + (n & 63)]
                        : WG[d * 256 + (n - 256)];
    qg[i] = f2bf(v);
  } else if (i < 262144) {               // [WkT | WvT]  512x256
    int j = i - 131072; int n = j >> 8, d = j & 255;
    float v = (n < 256) ? WK[((n >> 6) * 256 + d) * 64 + (n & 63)]
                        : WV[(((n - 256) >> 6) * 256 + d) * 64 + ((n - 256) & 63)];
    kv[j] = f2bf(v);
  } else if (i < 327680) {               // WoT 256x256
    int j = i - 262144; int n = j >> 8, d = j & 255;
    wo[j] = f2bf(WO[d * 256 + n]);
  } else if (i < 458752) {               // F1T 512x256
    int j = i - 327680; int n = j >> 8, d = j & 255;
    f1[j] = f2bf(F1[d * 512 + n]);
  } else if (i < 589824) {               // F2T 256x512
    int j = i - 458752; int n = j >> 9, k = j & 511;
    f2[j] = f2bf(F2[k * 256 + n]);
  }
}

// ---------------- LayerNorm over 256, one wave per row, output bf16 ----------------
__global__ __launch_bounds__(256) void ln_fwd(
    const float* __restrict__ X, const float* __restrict__ W,
    const float* __restrict__ Bv, unsigned short* __restrict__ Y)
{
  int lane = threadIdx.x & 63;
  size_t row = (size_t)blockIdx.x * 4 + (threadIdx.x >> 6);
  const float4 v = *reinterpret_cast<const float4*>(X + row * 256 + lane * 4);
  float s = v.x + v.y + v.z + v.w;
  #pragma unroll
  for (int off = 1; off < 64; off <<= 1) s += __shfl_xor(s, off);
  float mean = s * (1.0f / 256.0f);
  float dx = v.x - mean, dy = v.y - mean, dz = v.z - mean, dw = v.w - mean;
  float q = dx * dx + dy * dy + dz * dz + dw * dw;
  #pragma unroll
  for (int off = 1; off < 64; off <<= 1) q += __shfl_xor(q, off);
  float rstd = rsqrtf(q * (1.0f / 256.0f) + 1e-5f);
  float4 wv = *reinterpret_cast<const float4*>(W + lane * 4);
  float4 bv = *reinterpret_cast<const float4*>(Bv + lane * 4);
  ushort4 o;
  o.x = f2bf(dx * rstd * wv.x + bv.x);
  o.y = f2bf(dy * rstd * wv.y + bv.y);
  o.z = f2bf(dz * rstd * wv.z + bv.z);
  o.w = f2bf(dw * rstd * wv.w + bv.w);
  *reinterpret_cast<ushort4*>(Y + row * 256 + lane * 4) = o;
}

// ---------------- NT GEMM: A[M,K]bf16 @ B[N,K]bf16 -> epilogue ----------------
// tile 128x64, BK=64, 4 waves (2x2). global_load_lds staging, pre-swizzled source.
// XCD remap: all n-blocks of one m-panel land on one XCD (A-panel L2 reuse).
// EPI: 0=QG(split bf16), 1=KV(bf16 + V transposed), 2=+resid->f32,
//      3=+bias,leakyrelu->bf16(stride 512), 4=+bias+resid->f32
template<int EPI>
__global__ __launch_bounds__(256) void gemm_nt(
    const unsigned short* __restrict__ A, const unsigned short* __restrict__ Bw,
    int K, unsigned short* __restrict__ o0, unsigned short* __restrict__ o1,
    const float* __restrict__ bias, const float* __restrict__ resid,
    float* __restrict__ of)
{
  __shared__ __align__(16) char sA[128 * 128];
  __shared__ __align__(16) char sB[64 * 128];
  const int tid = threadIdx.x, lane = tid & 63, w = tid >> 6;
  // gridDim.y == 128 always; remap so same-m0 blocks share an XCD
  const int flat = blockIdx.x + gridDim.x * blockIdx.y;
  const int c = flat & 7, jj = flat >> 3;
  const int m0 = (c * 16 + (jj & 15)) * 128;
  const int n0 = (jj >> 4) * 64;
  const int wr = (w >> 1) * 64, wc = (w & 1) * 32;
  const char* Ab = (const char*)A + (size_t)m0 * K * 2;
  const char* Bb = (const char*)Bw + (size_t)n0 * K * 2;
  const int srow = lane >> 3;                      // dest row & 7
  const int soff = 16 * ((lane & 7) ^ srow);       // pre-swizzled inner offset
  f32x4 acc[4][2] = {};

  for (int kt = 0; kt < K * 2; kt += 128) {   // kt = k-offset in bytes
    #pragma unroll
    for (int p = 0; p < 4; ++p) {
      int row = p * 32 + w * 8 + srow;
      gll16(Ab + (size_t)row * (K * 2) + kt + soff, &sA[p * 4096 + w * 1024]);
    }
    #pragma unroll
    for (int p = 0; p < 2; ++p) {
      int row = p * 32 + w * 8 + srow;
      gll16(Bb + (size_t)row * (K * 2) + kt + soff, &sB[p * 4096 + w * 1024]);
    }
    asm volatile("s_waitcnt vmcnt(0)" ::: "memory");
    __syncthreads();
    #pragma unroll
    for (int kk = 0; kk < 2; ++kk) {
      const int ib = kk * 64 + ((lane >> 4) * 16);
      bf16x8 af[4], bfr[2];
      #pragma unroll
      for (int rf = 0; rf < 4; ++rf) {
        int row = wr + rf * 16 + (lane & 15);
        af[rf] = *reinterpret_cast<const bf16x8*>(sA + row * 128 + (ib ^ ((row & 7) << 4)));
      }
      #pragma unroll
      for (int cf = 0; cf < 2; ++cf) {
        int row = wc + cf * 16 + (lane & 15);
        bfr[cf] = *reinterpret_cast<const bf16x8*>(sB + row * 128 + (ib ^ ((row & 7) << 4)));
      }
      #pragma unroll
      for (int rf = 0; rf < 4; ++rf)
        #pragma unroll
        for (int cf = 0; cf < 2; ++cf)
          acc[rf][cf] = __builtin_amdgcn_mfma_f32_16x16x32_bf16(af[rf], bfr[cf], acc[rf][cf], 0, 0, 0);
    }
    __syncthreads();
  }

  #pragma unroll
  for (int rf = 0; rf < 4; ++rf) {
    #pragma unroll
    for (int cf = 0; cf < 2; ++cf) {
      const int r0 = m0 + wr + rf * 16 + ((lane >> 4) * 4);
      const int col = n0 + wc + cf * 16 + (lane & 15);
      f32x4 v = acc[rf][cf];
      if constexpr (EPI == 0) {
        unsigned short* dst = (n0 < 256) ? o0 : o1;
        int ccol = col & 255;
        #pragma unroll
        for (int j = 0; j < 4; ++j) dst[(size_t)(r0 + j) * 256 + ccol] = f2bf(v[j]);
      } else if constexpr (EPI == 1) {
        if (n0 < 256) {
          #pragma unroll
          for (int j = 0; j < 4; ++j) o0[(size_t)(r0 + j) * 256 + col] = f2bf(v[j]);
        } else {
          int vc = col - 256, hh = vc >> 6, e = vc & 63;
          int bh = (r0 >> 10) * 4 + hh, s0 = r0 & 1023;
          ushort4 pk;
          pk.x = f2bf(v[0]); pk.y = f2bf(v[1]); pk.z = f2bf(v[2]); pk.w = f2bf(v[3]);
          *reinterpret_cast<ushort4*>(o1 + (((size_t)bh * 64 + e) << 10) + s0) = pk;
        }
      } else if constexpr (EPI == 2) {
        #pragma unroll
        for (int j = 0; j < 4; ++j) {
          size_t idx = (size_t)(r0 + j) * 256 + col;
          of[idx] = v[j] + resid[idx];
        }
      } else if constexpr (EPI == 3) {
        float bc = bias[col];
        #pragma unroll
        for (int j = 0; j < 4; ++j) {
          float t = v[j] + bc;
          o0[(size_t)(r0 + j) * 512 + col] = f2bf(t >= 0.0f ? t : 0.01f * t);
        }
      } else {
        float bc = bias[col];
        #pragma unroll
        for (int j = 0; j < 4; ++j) {
          size_t idx = (size_t)(r0 + j) * 256 + col;
          of[idx] = v[j] + bc + resid[idx];
        }
      }
    }
  }
}

// ---------------- retention: per (b,h,q-tile64) causal decay attention ----------------
// Q in registers; K/V double-buffered via global_load_lds (pre-swizzled source);
// one barrier per K-tile. XCD-clustered: all q-tiles of one bh on one XCD.
// qt dispatch order balances per-CU aggregate work (big tiles first).
__global__ __launch_bounds__(256) void attn_ret(
    const unsigned short* __restrict__ Qb, const unsigned short* __restrict__ Kb,
    const unsigned short* __restrict__ Vt, const unsigned short* __restrict__ Gb,
    const float* __restrict__ gnw, const float* __restrict__ gnb,
    unsigned short* __restrict__ AY)
{
  __shared__ __align__(16) char sK[2][8192];
  __shared__ __align__(16) char sV[2][8192];
  __shared__ __align__(16) char sP[8192];
  const int tid = threadIdx.x, lane = tid & 63, w = tid >> 6;
  const int id = blockIdx.x;
  const int c = id & 7, jid = id >> 3;
  const int bh = c * 8 + (jid & 7);              // all 16 q-tiles of bh share XCD c
  const int g = jid >> 3;
  const int qt = (g < 4) ? (15 - g) : (g < 8) ? (11 - g) : (g < 12) ? g : (g - 12);
  const int b = bh >> 2, h = bh & 3;

  const float la = logf(1.0f / 32.0f), lb = logf(1.0f / 512.0f);
  const float gamma = 1.0f - expf(la + (lb - la) * ((float)h * (1.0f / 3.0f)));
  const float lg = log2f(gamma);

  // Q fragments directly into registers (16B contiguous per lane per kk)
  const char* Qg = (const char*)Qb
      + ((size_t)(b * 1024 + qt * 64 + w * 16 + (lane & 15))) * 512 + h * 128 + (lane >> 4) * 16;
  const bf16x8 aq0 = *reinterpret_cast<const bf16x8*>(Qg);
  const bf16x8 aq1 = *reinterpret_cast<const bf16x8*>(Qg + 64);

  const int nloc_b = w * 16 + ((lane >> 4) * 4);
  float Aj[4], Bcf[4];
  #pragma unroll
  for (int j = 0; j < 4; ++j) Aj[j] = exp2f((float)(qt * 64 + nloc_b + j) * lg);
  #pragma unroll
  for (int cf = 0; cf < 4; ++cf) Bcf[cf] = exp2f(-(float)(cf * 16 + (lane & 15)) * lg);
  const float g64 = exp2f(-64.0f * lg);

  const char* Kg = (const char*)Kb + ((size_t)(b * 1024)) * 512 + h * 128;
  const char* Vg = (const char*)Vt + ((size_t)bh * 64) * 2048;
  const int srow = lane >> 3;
  const int soff = 16 * ((lane & 7) ^ srow);

  auto stage = [&](int bufi, int t) {
    const char* kb = Kg + (size_t)(t * 64) * 512;
    const char* vb = Vg + (size_t)(t * 64) * 2;
    #pragma unroll
    for (int p = 0; p < 2; ++p) {
      int row = p * 32 + w * 8 + srow;
      gll16(kb + (size_t)row * 512 + soff, &sK[bufi][p * 4096 + w * 1024]);
      gll16(vb + (size_t)row * 2048 + soff, &sV[bufi][p * 4096 + w * 1024]);
    }
  };

  stage(0, 0);
  f32x4 o[4] = {};
  asm volatile("s_waitcnt vmcnt(0)" ::: "memory");
  __syncthreads();
  int buf = 0;

  for (int t = 0; t <= qt; ++t) {
    if (t < qt) stage(buf ^ 1, t + 1);   // prefetch next tile into other buffer

    // QK^T: s4[cf] = Q(this wave's 16 rows) x K(64 keys)
    f32x4 s4[4] = {};
    #pragma unroll
    for (int kk = 0; kk < 2; ++kk) {
      const int ib = kk * 64 + ((lane >> 4) * 16);
      const bf16x8 aq = kk ? aq1 : aq0;
      #pragma unroll
      for (int cf = 0; cf < 4; ++cf) {
        int kr = cf * 16 + (lane & 15);
        bf16x8 bk = *reinterpret_cast<const bf16x8*>(&sK[buf][kr * 128 + (ib ^ ((kr & 7) << 4))]);
        s4[cf] = __builtin_amdgcn_mfma_f32_16x16x32_bf16(aq, bk, s4[cf], 0, 0, 0);
      }
    }

    // decay + causal mask, write P (wave-private rows) as bf16
    const bool diag = (t == qt);
    #pragma unroll
    for (int cf = 0; cf < 4; ++cf) {
      const int mloc = cf * 16 + (lane & 15);
      #pragma unroll
      for (int j = 0; j < 4; ++j) {
        float p = s4[cf][j] * (Aj[j] * Bcf[cf]);
        if (diag && (nloc_b + j - mloc) < 0) p = 0.0f;
        int pr = nloc_b + j;
        *reinterpret_cast<unsigned short*>(sP + pr * 128 + ((mloc * 2) ^ ((pr & 7) << 4))) = f2bf(p);
      }
    }

    // PV: o[cf(e-block)] += P x V^T
    #pragma unroll
    for (int kk = 0; kk < 2; ++kk) {
      const int ib = kk * 64 + ((lane >> 4) * 16);
      int pr = w * 16 + (lane & 15);
      bf16x8 ap = *reinterpret_cast<const bf16x8*>(sP + pr * 128 + (ib ^ ((pr & 7) << 4)));
      #pragma unroll
      for (int cf = 0; cf < 4; ++cf) {
        int vr = cf * 16 + (lane & 15);
        bf16x8 bv = *reinterpret_cast<const bf16x8*>(&sV[buf][vr * 128 + (ib ^ ((vr & 7) << 4))]);
        o[cf] = __builtin_amdgcn_mfma_f32_16x16x32_bf16(ap, bv, o[cf], 0, 0, 0);
      }
    }
    #pragma unroll
    for (int j = 0; j < 4; ++j) Aj[j] *= g64;

    asm volatile("s_waitcnt vmcnt(0)" ::: "memory");
    __syncthreads();
    buf ^= 1;
  }

  // GroupNorm per (token,head) over 64 + gn affine + swish(G) gate -> bf16
  float gw[4], gb[4];
  #pragma unroll
  for (int cf = 0; cf < 4; ++cf) {
    int col = h * 64 + cf * 16 + (lane & 15);
    gw[cf] = gnw[col]; gb[cf] = gnb[col];
  }
  const int tokb = b * 1024 + qt * 64 + nloc_b;
  #pragma unroll
  for (int j = 0; j < 4; ++j) {
    float sm = 0.0f, sq = 0.0f;
    #pragma unroll
    for (int cf = 0; cf < 4; ++cf) { float xv = o[cf][j]; sm += xv; sq += xv * xv; }
    #pragma unroll
    for (int off = 1; off < 16; off <<= 1) { sm += __shfl_xor(sm, off); sq += __shfl_xor(sq, off); }
    float mean = sm * (1.0f / 64.0f);
    float var = sq * (1.0f / 64.0f) - mean * mean;
    float rstd = rsqrtf(var + 1e-5f);
    size_t tok = (size_t)(tokb + j);
    #pragma unroll
    for (int cf = 0; cf < 4; ++cf) {
      int col = h * 64 + cf * 16 + (lane & 15);
      float yn = (o[cf][j] - mean) * rstd * gw[cf] + gb[cf];
      float gv = bf2f(Gb[tok * 256 + col]);
      float sg = gv / (1.0f + expf(-gv));
      AY[tok * 256 + col] = f2bf(yn * sg);
    }
  }
}

// ---------------- launch ----------------
extern "C" void kernel_launch(void* const* d_in, const int* in_sizes, int n_in,
                              void* d_out, int out_size, void* d_ws, size_t ws_size,
                              hipStream_t stream) {
  const float* x     = (const float*)d_in[0];
  const float* y     = (const float*)d_in[1];
  const float* ln1_w = (const float*)d_in[2];
  const float* ln1_b = (const float*)d_in[3];
  const float* W_Q   = (const float*)d_in[4];
  const float* W_K   = (const float*)d_in[5];
  const float* W_V   = (const float*)d_in[6];
  const float* gn_w  = (const float*)d_in[7];
  const float* gn_b  = (const float*)d_in[8];
  const float* W_G   = (const float*)d_in[9];
  const float* W_O   = (const float*)d_in[10];
  const float* ln2_w = (const float*)d_in[11];
  const float* ln2_b = (const float*)d_in[12];
  const float* ff_w1 = (const float*)d_in[13];
  const float* ff_b1 = (const float*)d_in[14];
  const float* ff_w2 = (const float*)d_in[15];
  const float* ff_b2 = (const float*)d_in[16];

  char* ws = (char*)d_ws;
  const size_t MB = 1048576;
  unsigned short* XN  = (unsigned short*)(ws + 0 * MB);
  unsigned short* ZN  = (unsigned short*)(ws + 8 * MB);
  unsigned short* QB  = (unsigned short*)(ws + 16 * MB);
  unsigned short* KB  = (unsigned short*)(ws + 24 * MB);
  unsigned short* VT  = (unsigned short*)(ws + 32 * MB);
  unsigned short* GB  = (unsigned short*)(ws + 40 * MB);
  unsigned short* WQG = (unsigned short*)(ws + 48 * MB);
  unsigned short* WKV = (unsigned short*)(ws + 48 * MB + 262144);
  unsigned short* WOp = (unsigned short*)(ws + 48 * MB + 524288);
  unsigned short* F1p = (unsigned short*)(ws + 48 * MB + 655360);
  unsigned short* F2p = (unsigned short*)(ws + 48 * MB + 917504);
  float*          X1  = (float*)(ws + 16 * MB);
  unsigned short* X1N = (unsigned short*)(ws + 32 * MB);
  unsigned short* H   = (unsigned short*)(ws + 0 * MB);
  unsigned short* AY  = ZN;
  float* out = (float*)d_out;

  pack_w<<<2304, 256, 0, stream>>>(W_Q, W_K, W_V, W_G, W_O, ff_w1, ff_w2,
                                   WQG, WKV, WOp, F1p, F2p);
  ln_fwd<<<4096, 256, 0, stream>>>(x, ln1_w, ln1_b, XN);
  ln_fwd<<<4096, 256, 0, stream>>>(y, ln1_w, ln1_b, ZN);
  gemm_nt<0><<<dim3(8, 128), 256, 0, stream>>>(XN, WQG, 256, QB, GB, nullptr, nullptr, nullptr);
  gemm_nt<1><<<dim3(8, 128), 256, 0, stream>>>(ZN, WKV, 256, KB, VT, nullptr, nullptr, nullptr);
  attn_ret<<<1024, 256, 0, stream>>>(QB, KB, VT, GB, gn_w, gn_b, AY);
  gemm_nt<2><<<dim3(4, 128), 256, 0, stream>>>(AY, WOp, 256, nullptr, nullptr, nullptr, x, X1);
  ln_fwd<<<4096, 256, 0, stream>>>(X1, ln2_w, ln2_b, X1N);
  gemm_nt<3><<<dim3(8, 128), 256, 0, stream>>>(X1N, F1p, 256, H, nullptr, ff_b1, nullptr, nullptr);
  gemm_nt<4><<<dim3(4, 128), 256, 0, stream>>>(H, F2p, 512, nullptr, nullptr, ff_b2, X1, out);
}

// Round 3
// 100.467 us; speedup vs baseline: 1.6643x; 1.0902x over previous
//
#include <hip/hip_runtime.h>

typedef float f32x4 __attribute__((ext_vector_type(4)));
typedef short bf16x8 __attribute__((ext_vector_type(8)));

__device__ __forceinline__ unsigned short f2bf(float f) {
  unsigned int u = __builtin_bit_cast(unsigned int, f);
  u += 0x7fffu + ((u >> 16) & 1u);
  return (unsigned short)(u >> 16);
}
__device__ __forceinline__ float bf2f(unsigned short s) {
  unsigned int u = ((unsigned int)s) << 16;
  return __builtin_bit_cast(float, u);
}

// async global->LDS, 16B per lane. LDS dest = wave-uniform base + lane*16.
__device__ __forceinline__ void gll16(const void* src, void* dst) {
  __builtin_amdgcn_global_load_lds((const __attribute__((address_space(1))) void*)src,
                                   (__attribute__((address_space(3))) void*)dst, 16, 0, 0);
}

// ---------------- prep: ln(x)->XN, ln(y)->ZN, pack all weights to bf16 [N][K] ----------------
__global__ __launch_bounds__(256) void prep(
    const float* __restrict__ x, const float* __restrict__ y,
    const float* __restrict__ ln1w, const float* __restrict__ ln1b,
    const float* __restrict__ WQ, const float* __restrict__ WK,
    const float* __restrict__ WV, const float* __restrict__ WG,
    const float* __restrict__ WO, const float* __restrict__ F1,
    const float* __restrict__ F2,
    unsigned short* __restrict__ XN, unsigned short* __restrict__ ZN,
    unsigned short* __restrict__ qg, unsigned short* __restrict__ kv,
    unsigned short* __restrict__ wo, unsigned short* __restrict__ f1,
    unsigned short* __restrict__ f2)
{
  const int id = blockIdx.x;
  if (id < 8192) {
    const float* X = (id < 4096) ? x : y;
    unsigned short* Y = (id < 4096) ? XN : ZN;
    const int bid = id & 4095;
    const int lane = threadIdx.x & 63;
    const size_t row = (size_t)bid * 4 + (threadIdx.x >> 6);
    const float4 v = *reinterpret_cast<const float4*>(X + row * 256 + lane * 4);
    float s = v.x + v.y + v.z + v.w;
    #pragma unroll
    for (int off = 1; off < 64; off <<= 1) s += __shfl_xor(s, off);
    float mean = s * (1.0f / 256.0f);
    float dx = v.x - mean, dy = v.y - mean, dz = v.z - mean, dw = v.w - mean;
    float q = dx * dx + dy * dy + dz * dz + dw * dw;
    #pragma unroll
    for (int off = 1; off < 64; off <<= 1) q += __shfl_xor(q, off);
    float rstd = rsqrtf(q * (1.0f / 256.0f) + 1e-5f);
    float4 wv = *reinterpret_cast<const float4*>(ln1w + lane * 4);
    float4 bv = *reinterpret_cast<const float4*>(ln1b + lane * 4);
    ushort4 o;
    o.x = f2bf(dx * rstd * wv.x + bv.x);
    o.y = f2bf(dy * rstd * wv.y + bv.y);
    o.z = f2bf(dz * rstd * wv.z + bv.z);
    o.w = f2bf(dw * rstd * wv.w + bv.w);
    *reinterpret_cast<ushort4*>(Y + row * 256 + lane * 4) = o;
    return;
  }
  int i = (id - 8192) * 256 + threadIdx.x;
  if (i < 131072) {                      // [WqT | WgT]  512x256
    int n = i >> 8, d = i & 255;
    float v = (n < 256) ? WQ[((n >> 6) * 256 + d) * 64 + (n & 63)]
                        : WG[d * 256 + (n - 256)];
    qg[i] = f2bf(v);
  } else if (i < 262144) {               // [WkT | WvT]  512x256
    int j = i - 131072; int n = j >> 8, d = j & 255;
    float v = (n < 256) ? WK[((n >> 6) * 256 + d) * 64 + (n & 63)]
                        : WV[(((n - 256) >> 6) * 256 + d) * 64 + ((n - 256) & 63)];
    kv[j] = f2bf(v);
  } else if (i < 327680) {               // WoT 256x256
    int j = i - 262144; int n = j >> 8, d = j & 255;
    wo[j] = f2bf(WO[d * 256 + n]);
  } else if (i < 458752) {               // F1T 512x256
    int j = i - 327680; int n = j >> 8, d = j & 255;
    f1[j] = f2bf(F1[d * 512 + n]);
  } else if (i < 589824) {               // F2T 256x512
    int j = i - 458752; int n = j >> 9, k = j & 511;
    f2[j] = f2bf(F2[k * 256 + n]);
  }
}

// ---------------- QKVG: two NT GEMMs (z=0: XN@WQG -> Q|G, z=1: ZN@WKV -> K|Vt) ----------------
// tile 128x64, BK=64, 4 waves, double-buffered global_load_lds prefetch.
__global__ __launch_bounds__(256) void gemm_qkvg(
    const unsigned short* __restrict__ XN, const unsigned short* __restrict__ ZN,
    const unsigned short* __restrict__ WQG, const unsigned short* __restrict__ WKV,
    unsigned short* __restrict__ QB, unsigned short* __restrict__ GB,
    unsigned short* __restrict__ KB, unsigned short* __restrict__ VT)
{
  __shared__ __align__(16) char sA[2][16384];
  __shared__ __align__(16) char sB[2][8192];
  const int tid = threadIdx.x, lane = tid & 63, w = tid >> 6;
  const int z = blockIdx.z;
  const unsigned short* A = z ? ZN : XN;
  const unsigned short* Bw = z ? WKV : WQG;
  const int flat = blockIdx.x + 8 * blockIdx.y;
  const int c = flat & 7, jj = flat >> 3;
  const int m0 = (c * 16 + (jj & 15)) * 128;
  const int n0 = (jj >> 4) * 64;
  const int wr = (w >> 1) * 64, wc = (w & 1) * 32;
  const char* Ab = (const char*)A + (size_t)m0 * 512;
  const char* Bb = (const char*)Bw + (size_t)n0 * 512;
  const int srow = lane >> 3;
  const int soff = 16 * ((lane & 7) ^ srow);
  f32x4 acc[4][2] = {};

  auto stage = [&](int bufi, int kt) {
    #pragma unroll
    for (int p = 0; p < 4; ++p) {
      int row = p * 32 + w * 8 + srow;
      gll16(Ab + (size_t)row * 512 + kt + soff, &sA[bufi][p * 4096 + w * 1024]);
    }
    #pragma unroll
    for (int p = 0; p < 2; ++p) {
      int row = p * 32 + w * 8 + srow;
      gll16(Bb + (size_t)row * 512 + kt + soff, &sB[bufi][p * 4096 + w * 1024]);
    }
  };

  stage(0, 0);
  asm volatile("s_waitcnt vmcnt(0)" ::: "memory");
  __syncthreads();
  int buf = 0;
  for (int kt = 0; kt < 512; kt += 128) {
    if (kt + 128 < 512) stage(buf ^ 1, kt + 128);
    #pragma unroll
    for (int kk = 0; kk < 2; ++kk) {
      const int ib = kk * 64 + ((lane >> 4) * 16);
      bf16x8 af[4], bfr[2];
      #pragma unroll
      for (int rf = 0; rf < 4; ++rf) {
        int row = wr + rf * 16 + (lane & 15);
        af[rf] = *reinterpret_cast<const bf16x8*>(&sA[buf][row * 128 + (ib ^ ((row & 7) << 4))]);
      }
      #pragma unroll
      for (int cf = 0; cf < 2; ++cf) {
        int row = wc + cf * 16 + (lane & 15);
        bfr[cf] = *reinterpret_cast<const bf16x8*>(&sB[buf][row * 128 + (ib ^ ((row & 7) << 4))]);
      }
      #pragma unroll
      for (int rf = 0; rf < 4; ++rf)
        #pragma unroll
        for (int cf = 0; cf < 2; ++cf)
          acc[rf][cf] = __builtin_amdgcn_mfma_f32_16x16x32_bf16(af[rf], bfr[cf], acc[rf][cf], 0, 0, 0);
    }
    asm volatile("s_waitcnt vmcnt(0)" ::: "memory");
    __syncthreads();
    buf ^= 1;
  }

  #pragma unroll
  for (int rf = 0; rf < 4; ++rf) {
    #pragma unroll
    for (int cf = 0; cf < 2; ++cf) {
      const int r0 = m0 + wr + rf * 16 + ((lane >> 4) * 4);
      const int col = n0 + wc + cf * 16 + (lane & 15);
      f32x4 v = acc[rf][cf];
      if (z == 0) {
        unsigned short* dst = (n0 < 256) ? QB : GB;
        int ccol = col & 255;
        #pragma unroll
        for (int j = 0; j < 4; ++j) dst[(size_t)(r0 + j) * 256 + ccol] = f2bf(v[j]);
      } else {
        if (n0 < 256) {
          #pragma unroll
          for (int j = 0; j < 4; ++j) KB[(size_t)(r0 + j) * 256 + col] = f2bf(v[j]);
        } else {
          int vc = col - 256, hh = vc >> 6, e = vc & 63;
          int bh = (r0 >> 10) * 4 + hh, s0 = r0 & 1023;
          ushort4 pk;
          pk.x = f2bf(v[0]); pk.y = f2bf(v[1]); pk.z = f2bf(v[2]); pk.w = f2bf(v[3]);
          *reinterpret_cast<ushort4*>(VT + (((size_t)bh * 64 + e) << 10) + s0) = pk;
        }
      }
    }
  }
}

// ---------------- NT GEMM (FFN): tile 128x64, dbuf prefetch ----------------
// EPI: 3=+bias,leakyrelu->bf16(stride 512), 4=+bias+resid->f32
template<int EPI>
__global__ __launch_bounds__(256) void gemm_nt(
    const unsigned short* __restrict__ A, const unsigned short* __restrict__ Bw,
    int K, unsigned short* __restrict__ o0,
    const float* __restrict__ bias, const float* __restrict__ resid,
    float* __restrict__ of)
{
  __shared__ __align__(16) char sA[2][16384];
  __shared__ __align__(16) char sB[2][8192];
  const int tid = threadIdx.x, lane = tid & 63, w = tid >> 6;
  const int flat = blockIdx.x + gridDim.x * blockIdx.y;
  const int c = flat & 7, jj = flat >> 3;
  const int m0 = (c * 16 + (jj & 15)) * 128;
  const int n0 = (jj >> 4) * 64;
  const int wr = (w >> 1) * 64, wc = (w & 1) * 32;
  const int K2 = K * 2;
  const char* Ab = (const char*)A + (size_t)m0 * K2;
  const char* Bb = (const char*)Bw + (size_t)n0 * K2;
  const int srow = lane >> 3;
  const int soff = 16 * ((lane & 7) ^ srow);
  f32x4 acc[4][2] = {};

  auto stage = [&](int bufi, int kt) {
    #pragma unroll
    for (int p = 0; p < 4; ++p) {
      int row = p * 32 + w * 8 + srow;
      gll16(Ab + (size_t)row * K2 + kt + soff, &sA[bufi][p * 4096 + w * 1024]);
    }
    #pragma unroll
    for (int p = 0; p < 2; ++p) {
      int row = p * 32 + w * 8 + srow;
      gll16(Bb + (size_t)row * K2 + kt + soff, &sB[bufi][p * 4096 + w * 1024]);
    }
  };

  stage(0, 0);
  asm volatile("s_waitcnt vmcnt(0)" ::: "memory");
  __syncthreads();
  int buf = 0;
  for (int kt = 0; kt < K2; kt += 128) {
    if (kt + 128 < K2) stage(buf ^ 1, kt + 128);
    #pragma unroll
    for (int kk = 0; kk < 2; ++kk) {
      const int ib = kk * 64 + ((lane >> 4) * 16);
      bf16x8 af[4], bfr[2];
      #pragma unroll
      for (int rf = 0; rf < 4; ++rf) {
        int row = wr + rf * 16 + (lane & 15);
        af[rf] = *reinterpret_cast<const bf16x8*>(&sA[buf][row * 128 + (ib ^ ((row & 7) << 4))]);
      }
      #pragma unroll
      for (int cf = 0; cf < 2; ++cf) {
        int row = wc + cf * 16 + (lane & 15);
        bfr[cf] = *reinterpret_cast<const bf16x8*>(&sB[buf][row * 128 + (ib ^ ((row & 7) << 4))]);
      }
      #pragma unroll
      for (int rf = 0; rf < 4; ++rf)
        #pragma unroll
        for (int cf = 0; cf < 2; ++cf)
          acc[rf][cf] = __builtin_amdgcn_mfma_f32_16x16x32_bf16(af[rf], bfr[cf], acc[rf][cf], 0, 0, 0);
    }
    asm volatile("s_waitcnt vmcnt(0)" ::: "memory");
    __syncthreads();
    buf ^= 1;
  }

  #pragma unroll
  for (int rf = 0; rf < 4; ++rf) {
    #pragma unroll
    for (int cf = 0; cf < 2; ++cf) {
      const int r0 = m0 + wr + rf * 16 + ((lane >> 4) * 4);
      const int col = n0 + wc + cf * 16 + (lane & 15);
      f32x4 v = acc[rf][cf];
      if constexpr (EPI == 3) {
        float bc = bias[col];
        #pragma unroll
        for (int j = 0; j < 4; ++j) {
          float t = v[j] + bc;
          o0[(size_t)(r0 + j) * 512 + col] = f2bf(t >= 0.0f ? t : 0.01f * t);
        }
      } else {
        float bc = bias[col];
        #pragma unroll
        for (int j = 0; j < 4; ++j) {
          size_t idx = (size_t)(r0 + j) * 256 + col;
          of[idx] = v[j] + bc + resid[idx];
        }
      }
    }
  }
}

// ---------------- W_O GEMM + residual + fused LayerNorm ----------------
// tile 32x256 (full row), 4 waves (each 32x64), BK=64, dbuf prefetch.
// out: X1 (f32, x1 = AY@WoT + x) and X1N (bf16, LN(x1))
__global__ __launch_bounds__(256) void gemm_wo_ln(
    const unsigned short* __restrict__ AY, const unsigned short* __restrict__ WoT,
    const float* __restrict__ x, const float* __restrict__ ln2w,
    const float* __restrict__ ln2b,
    float* __restrict__ X1, unsigned short* __restrict__ X1N)
{
  __shared__ __align__(16) char sA[2][4096];
  __shared__ __align__(16) char sB[2][32768];
  __shared__ float redS[32][4], redQ[32][4];
  const int tid = threadIdx.x, lane = tid & 63, w = tid >> 6;
  const int id = blockIdx.x;
  const int c = id & 7, j5 = id >> 3;
  const int m0 = (c * 64 + j5) * 32;
  const char* Ab = (const char*)AY + (size_t)m0 * 512;
  const char* Bb = (const char*)WoT;
  const int srow = lane >> 3;
  const int soff = 16 * ((lane & 7) ^ srow);
  f32x4 acc[2][4] = {};

  auto stage = [&](int bufi, int kt) {
    {
      int row = w * 8 + srow;
      gll16(Ab + (size_t)row * 512 + kt + soff, &sA[bufi][w * 1024]);
    }
    #pragma unroll
    for (int p = 0; p < 8; ++p) {
      int row = w * 64 + p * 8 + srow;
      gll16(Bb + (size_t)row * 512 + kt + soff, &sB[bufi][w * 8192 + p * 1024]);
    }
  };

  stage(0, 0);
  asm volatile("s_waitcnt vmcnt(0)" ::: "memory");
  __syncthreads();
  int buf = 0;
  for (int kt = 0; kt < 512; kt += 128) {
    if (kt + 128 < 512) stage(buf ^ 1, kt + 128);
    #pragma unroll
    for (int kk = 0; kk < 2; ++kk) {
      const int ib = kk * 64 + ((lane >> 4) * 16);
      bf16x8 af[2], bfr[4];
      #pragma unroll
      for (int mf = 0; mf < 2; ++mf) {
        int row = mf * 16 + (lane & 15);
        af[mf] = *reinterpret_cast<const bf16x8*>(&sA[buf][row * 128 + (ib ^ ((row & 7) << 4))]);
      }
      #pragma unroll
      for (int nf = 0; nf < 4; ++nf) {
        int row = w * 64 + nf * 16 + (lane & 15);
        bfr[nf] = *reinterpret_cast<const bf16x8*>(&sB[buf][row * 128 + (ib ^ ((row & 7) << 4))]);
      }
      #pragma unroll
      for (int mf = 0; mf < 2; ++mf)
        #pragma unroll
        for (int nf = 0; nf < 4; ++nf)
          acc[mf][nf] = __builtin_amdgcn_mfma_f32_16x16x32_bf16(af[mf], bfr[nf], acc[mf][nf], 0, 0, 0);
    }
    asm volatile("s_waitcnt vmcnt(0)" ::: "memory");
    __syncthreads();
    buf ^= 1;
  }

  // add residual x, accumulate row partial sums
  #pragma unroll
  for (int mf = 0; mf < 2; ++mf) {
    #pragma unroll
    for (int j = 0; j < 4; ++j) {
      const int rowg = m0 + mf * 16 + ((lane >> 4) * 4) + j;
      float s = 0.0f, q = 0.0f;
      #pragma unroll
      for (int nf = 0; nf < 4; ++nf) {
        const int col = w * 64 + nf * 16 + (lane & 15);
        float v = acc[mf][nf][j] + x[(size_t)rowg * 256 + col];
        acc[mf][nf][j] = v;
        s += v; q += v * v;
      }
      #pragma unroll
      for (int off = 1; off < 16; off <<= 1) { s += __shfl_xor(s, off); q += __shfl_xor(q, off); }
      if ((lane & 15) == 0) {
        int rl = mf * 16 + ((lane >> 4) * 4) + j;
        redS[rl][w] = s; redQ[rl][w] = q;
      }
    }
  }
  __syncthreads();
  #pragma unroll
  for (int mf = 0; mf < 2; ++mf) {
    #pragma unroll
    for (int j = 0; j < 4; ++j) {
      const int rl = mf * 16 + ((lane >> 4) * 4) + j;
      const int rowg = m0 + rl;
      float sm = redS[rl][0] + redS[rl][1] + redS[rl][2] + redS[rl][3];
      float sq = redQ[rl][0] + redQ[rl][1] + redQ[rl][2] + redQ[rl][3];
      float mean = sm * (1.0f / 256.0f);
      float var = sq * (1.0f / 256.0f) - mean * mean;
      float rstd = rsqrtf(var + 1e-5f);
      #pragma unroll
      for (int nf = 0; nf < 4; ++nf) {
        const int col = w * 64 + nf * 16 + (lane & 15);
        float v = acc[mf][nf][j];
        X1[(size_t)rowg * 256 + col] = v;
        X1N[(size_t)rowg * 256 + col] = f2bf((v - mean) * rstd * ln2w[col] + ln2b[col]);
      }
    }
  }
}

// ---------------- retention: per (b,h,q-tile64) causal decay attention ----------------
__global__ __launch_bounds__(256) void attn_ret(
    const unsigned short* __restrict__ Qb, const unsigned short* __restrict__ Kb,
    const unsigned short* __restrict__ Vt, const unsigned short* __restrict__ Gb,
    const float* __restrict__ gnw, const float* __restrict__ gnb,
    unsigned short* __restrict__ AY)
{
  __shared__ __align__(16) char sK[2][8192];
  __shared__ __align__(16) char sV[2][8192];
  __shared__ __align__(16) char sP[8192];
  const int tid = threadIdx.x, lane = tid & 63, w = tid >> 6;
  const int id = blockIdx.x;
  const int c = id & 7, jid = id >> 3;
  const int bh = c * 8 + (jid & 7);
  const int g = jid >> 3;
  const int qt = (g < 4) ? (15 - g) : (g < 8) ? (11 - g) : (g < 12) ? g : (g - 12);
  const int b = bh >> 2, h = bh & 3;

  const float la = logf(1.0f / 32.0f), lb = logf(1.0f / 512.0f);
  const float gamma = 1.0f - expf(la + (lb - la) * ((float)h * (1.0f / 3.0f)));
  const float lg = log2f(gamma);

  const char* Qg = (const char*)Qb
      + ((size_t)(b * 1024 + qt * 64 + w * 16 + (lane & 15))) * 512 + h * 128 + (lane >> 4) * 16;
  const bf16x8 aq0 = *reinterpret_cast<const bf16x8*>(Qg);
  const bf16x8 aq1 = *reinterpret_cast<const bf16x8*>(Qg + 64);

  const int nloc_b = w * 16 + ((lane >> 4) * 4);
  float Aj[4], Bcf[4];
  #pragma unroll
  for (int j = 0; j < 4; ++j) Aj[j] = exp2f((float)(qt * 64 + nloc_b + j) * lg);
  #pragma unroll
  for (int cf = 0; cf < 4; ++cf) Bcf[cf] = exp2f(-(float)(cf * 16 + (lane & 15)) * lg);
  const float g64 = exp2f(-64.0f * lg);

  const char* Kg = (const char*)Kb + ((size_t)(b * 1024)) * 512 + h * 128;
  const char* Vg = (const char*)Vt + ((size_t)bh * 64) * 2048;
  const int srow = lane >> 3;
  const int soff = 16 * ((lane & 7) ^ srow);

  auto stage = [&](int bufi, int t) {
    const char* kb = Kg + (size_t)(t * 64) * 512;
    const char* vb = Vg + (size_t)(t * 64) * 2;
    #pragma unroll
    for (int p = 0; p < 2; ++p) {
      int row = p * 32 + w * 8 + srow;
      gll16(kb + (size_t)row * 512 + soff, &sK[bufi][p * 4096 + w * 1024]);
      gll16(vb + (size_t)row * 2048 + soff, &sV[bufi][p * 4096 + w * 1024]);
    }
  };

  stage(0, 0);
  f32x4 o[4] = {};
  asm volatile("s_waitcnt vmcnt(0)" ::: "memory");
  __syncthreads();
  int buf = 0;

  for (int t = 0; t <= qt; ++t) {
    if (t < qt) stage(buf ^ 1, t + 1);

    f32x4 s4[4] = {};
    #pragma unroll
    for (int kk = 0; kk < 2; ++kk) {
      const int ib = kk * 64 + ((lane >> 4) * 16);
      const bf16x8 aq = kk ? aq1 : aq0;
      #pragma unroll
      for (int cf = 0; cf < 4; ++cf) {
        int kr = cf * 16 + (lane & 15);
        bf16x8 bk = *reinterpret_cast<const bf16x8*>(&sK[buf][kr * 128 + (ib ^ ((kr & 7) << 4))]);
        s4[cf] = __builtin_amdgcn_mfma_f32_16x16x32_bf16(aq, bk, s4[cf], 0, 0, 0);
      }
    }

    const bool diag = (t == qt);
    #pragma unroll
    for (int cf = 0; cf < 4; ++cf) {
      const int mloc = cf * 16 + (lane & 15);
      #pragma unroll
      for (int j = 0; j < 4; ++j) {
        float p = s4[cf][j] * (Aj[j] * Bcf[cf]);
        if (diag && (nloc_b + j - mloc) < 0) p = 0.0f;
        int pr = nloc_b + j;
        *reinterpret_cast<unsigned short*>(sP + pr * 128 + ((mloc * 2) ^ ((pr & 7) << 4))) = f2bf(p);
      }
    }

    #pragma unroll
    for (int kk = 0; kk < 2; ++kk) {
      const int ib = kk * 64 + ((lane >> 4) * 16);
      int pr = w * 16 + (lane & 15);
      bf16x8 ap = *reinterpret_cast<const bf16x8*>(sP + pr * 128 + (ib ^ ((pr & 7) << 4)));
      #pragma unroll
      for (int cf = 0; cf < 4; ++cf) {
        int vr = cf * 16 + (lane & 15);
        bf16x8 bv = *reinterpret_cast<const bf16x8*>(&sV[buf][vr * 128 + (ib ^ ((vr & 7) << 4))]);
        o[cf] = __builtin_amdgcn_mfma_f32_16x16x32_bf16(ap, bv, o[cf], 0, 0, 0);
      }
    }
    #pragma unroll
    for (int j = 0; j < 4; ++j) Aj[j] *= g64;

    asm volatile("s_waitcnt vmcnt(0)" ::: "memory");
    __syncthreads();
    buf ^= 1;
  }

  float gw[4], gb[4];
  #pragma unroll
  for (int cf = 0; cf < 4; ++cf) {
    int col = h * 64 + cf * 16 + (lane & 15);
    gw[cf] = gnw[col]; gb[cf] = gnb[col];
  }
  const int tokb = b * 1024 + qt * 64 + nloc_b;
  #pragma unroll
  for (int j = 0; j < 4; ++j) {
    float sm = 0.0f, sq = 0.0f;
    #pragma unroll
    for (int cf = 0; cf < 4; ++cf) { float xv = o[cf][j]; sm += xv; sq += xv * xv; }
    #pragma unroll
    for (int off = 1; off < 16; off <<= 1) { sm += __shfl_xor(sm, off); sq += __shfl_xor(sq, off); }
    float mean = sm * (1.0f / 64.0f);
    float var = sq * (1.0f / 64.0f) - mean * mean;
    float rstd = rsqrtf(var + 1e-5f);
    size_t tok = (size_t)(tokb + j);
    #pragma unroll
    for (int cf = 0; cf < 4; ++cf) {
      int col = h * 64 + cf * 16 + (lane & 15);
      float yn = (o[cf][j] - mean) * rstd * gw[cf] + gb[cf];
      float gv = bf2f(Gb[tok * 256 + col]);
      float sg = gv / (1.0f + expf(-gv));
      AY[tok * 256 + col] = f2bf(yn * sg);
    }
  }
}

// ---------------- launch ----------------
extern "C" void kernel_launch(void* const* d_in, const int* in_sizes, int n_in,
                              void* d_out, int out_size, void* d_ws, size_t ws_size,
                              hipStream_t stream) {
  const float* x     = (const float*)d_in[0];
  const float* y     = (const float*)d_in[1];
  const float* ln1_w = (const float*)d_in[2];
  const float* ln1_b = (const float*)d_in[3];
  const float* W_Q   = (const float*)d_in[4];
  const float* W_K   = (const float*)d_in[5];
  const float* W_V   = (const float*)d_in[6];
  const float* gn_w  = (const float*)d_in[7];
  const float* gn_b  = (const float*)d_in[8];
  const float* W_G   = (const float*)d_in[9];
  const float* W_O   = (const float*)d_in[10];
  const float* ln2_w = (const float*)d_in[11];
  const float* ln2_b = (const float*)d_in[12];
  const float* ff_w1 = (const float*)d_in[13];
  const float* ff_b1 = (const float*)d_in[14];
  const float* ff_w2 = (const float*)d_in[15];
  const float* ff_b2 = (const float*)d_in[16];

  char* ws = (char*)d_ws;
  const size_t MB = 1048576;
  unsigned short* XN  = (unsigned short*)(ws + 0 * MB);
  unsigned short* ZN  = (unsigned short*)(ws + 8 * MB);
  unsigned short* QB  = (unsigned short*)(ws + 16 * MB);
  unsigned short* KB  = (unsigned short*)(ws + 24 * MB);
  unsigned short* VT  = (unsigned short*)(ws + 32 * MB);
  unsigned short* GB  = (unsigned short*)(ws + 40 * MB);
  unsigned short* WQG = (unsigned short*)(ws + 48 * MB);
  unsigned short* WKV = (unsigned short*)(ws + 48 * MB + 262144);
  unsigned short* WOp = (unsigned short*)(ws + 48 * MB + 524288);
  unsigned short* F1p = (unsigned short*)(ws + 48 * MB + 655360);
  unsigned short* F2p = (unsigned short*)(ws + 48 * MB + 917504);
  float*          X1  = (float*)(ws + 16 * MB);
  unsigned short* X1N = (unsigned short*)(ws + 32 * MB);
  unsigned short* H   = (unsigned short*)(ws + 0 * MB);
  unsigned short* AY  = ZN;
  float* out = (float*)d_out;

  prep<<<10496, 256, 0, stream>>>(x, y, ln1_w, ln1_b, W_Q, W_K, W_V, W_G, W_O,
                                  ff_w1, ff_w2, XN, ZN, WQG, WKV, WOp, F1p, F2p);
  gemm_qkvg<<<dim3(8, 128, 2), 256, 0, stream>>>(XN, ZN, WQG, WKV, QB, GB, KB, VT);
  attn_ret<<<1024, 256, 0, stream>>>(QB, KB, VT, GB, gn_w, gn_b, AY);
  gemm_wo_ln<<<512, 256, 0, stream>>>(AY, WOp, x, ln2_w, ln2_b, X1, X1N);
  gemm_nt<3><<<dim3(8, 128), 256, 0, stream>>>(X1N, F1p, 256, H, ff_b1, nullptr, nullptr);
  gemm_nt<4><<<dim3(4, 128), 256, 0, stream>>>(H, F2p, 512, nullptr, ff_b2, X1, out);
}